// Round 7
// baseline (1266.056 us; speedup 1.0000x reference)
//
#include <hip/hip_runtime.h>

// ---------------------------------------------------------------------------
// NGCF forward, algebraically refactored:
//   per layer: S[v] = sum_{e: dst=v} w_e * x[src_e],  c[v] = sum w_e
//   out[v] = leakyrelu( (S+x)@W1 + (x*S)@W2 + (c+1)*b1 + c*b2 ), row-L2-norm
//   xui[b] = sum_l dot(x_l[user_b], x_l[NUM_USERS+pos_b])
// Edge buckets (CSR by dst, packed int2{src, w-bits}) built once per call.
// Layer gather: edge-parallel float4 — lane=(edge-slot, dim-group), 16 edges
// per super-round, one meta->gather dependency level for deg<=16 nodes.
// ---------------------------------------------------------------------------

#define SCAN_TILE 4096  // 256 threads x 16 elems

__global__ __launch_bounds__(256) void init_x_kernel(
    const float* __restrict__ Gu, const float* __restrict__ Gi,
    float* __restrict__ x, int nu4, int nt4) {
  int i = blockIdx.x * 256 + threadIdx.x;
  if (i >= nt4) return;
  float4 v = (i < nu4) ? ((const float4*)Gu)[i] : ((const float4*)Gi)[i - nu4];
  ((float4*)x)[i] = v;
}

__global__ __launch_bounds__(256) void hist_kernel(
    const int* __restrict__ dst, int* __restrict__ counts, int E) {
  int e = blockIdx.x * 256 + threadIdx.x;
  if (e >= E) return;
  atomicAdd(&counts[dst[e]], 1);
}

// phase 1: per-tile sums
__global__ __launch_bounds__(256) void tile_sum_kernel(
    const int* __restrict__ counts, int* __restrict__ tsum, int n) {
  int tid = threadIdx.x;
  int lo = blockIdx.x * SCAN_TILE + tid * 16;
  int s = 0;
  if (lo + 16 <= n) {
    const int4* p = (const int4*)(counts + lo);
#pragma unroll
    for (int q = 0; q < 4; ++q) {
      int4 v = p[q];
      s += v.x + v.y + v.z + v.w;
    }
  } else {
    for (int i = lo; i < n && i < lo + 16; ++i) s += counts[i];
  }
#pragma unroll
  for (int m = 1; m < 64; m <<= 1) s += __shfl_xor(s, m, 64);
  __shared__ int red[4];
  if ((tid & 63) == 0) red[tid >> 6] = s;
  __syncthreads();
  if (tid == 0) tsum[blockIdx.x] = red[0] + red[1] + red[2] + red[3];
}

// phase 2: exclusive scan of tile sums (ntiles <= 64 -> one wave)
__global__ __launch_bounds__(64) void tile_scan_kernel(int* __restrict__ tsum,
                                                       int ntiles) {
  int lane = threadIdx.x;
  if (ntiles <= 64) {
    int v = (lane < ntiles) ? tsum[lane] : 0;
    int incl = v;
#pragma unroll
    for (int m = 1; m < 64; m <<= 1) {
      int t = __shfl_up(incl, m, 64);
      if (lane >= m) incl += t;
    }
    if (lane < ntiles) tsum[lane] = incl - v;
  } else if (lane == 0) {  // fallback, not expected at these sizes
    int run = 0;
    for (int i = 0; i < ntiles; ++i) {
      int t = tsum[i];
      tsum[i] = run;
      run += t;
    }
  }
}

// phase 3: per-tile exclusive scan + global offset -> starts, cursor
__global__ __launch_bounds__(256) void tile_write_kernel(
    const int* __restrict__ counts, const int* __restrict__ tsum,
    int* __restrict__ starts, int* __restrict__ cursor, int n) {
  int tid = threadIdx.x;
  int lo = blockIdx.x * SCAN_TILE + tid * 16;
  int c[16];
  int s = 0;
#pragma unroll
  for (int q = 0; q < 16; ++q) {
    int i = lo + q;
    int v = (i < n) ? counts[i] : 0;
    c[q] = v;
    s += v;
  }
  __shared__ int bs[256];
  bs[tid] = s;
  __syncthreads();
  int incl = s;
  for (int off = 1; off < 256; off <<= 1) {
    int t = (tid >= off) ? bs[tid - off] : 0;
    __syncthreads();
    incl += t;
    bs[tid] = incl;
    __syncthreads();
  }
  int run = tsum[blockIdx.x] + incl - s;
#pragma unroll
  for (int q = 0; q < 16; ++q) {
    int i = lo + q;
    if (i < n) {
      starts[i] = run;
      cursor[i] = run;
      run += c[q];
    }
  }
}

// pack {src, w-bits} into one 8B record -> single scattered store,
// and later a single meta load per edge in the layer kernel.
__global__ __launch_bounds__(256) void place_kernel(
    const int* __restrict__ src, const int* __restrict__ dst,
    const float* __restrict__ w, int* __restrict__ cursor,
    int2* __restrict__ ebuf, int E) {
  int e = blockIdx.x * 256 + threadIdx.x;
  if (e >= E) return;
  int p = atomicAdd(&cursor[dst[e]], 1);
  ebuf[p] = make_int2(src[e], __float_as_int(w[e]));
}

// one wave per batch element; lane = dim; accumulate per-layer dot into out
__global__ __launch_bounds__(256) void dot_kernel(
    const float* __restrict__ x, const int* __restrict__ user,
    const int* __restrict__ pos, float* __restrict__ out,
    int batch, int nusers, int accumulate) {
  int b = blockIdx.x * 4 + (threadIdx.x >> 6);
  int lane = threadIdx.x & 63;
  if (b >= batch) return;
  int u = user[b];
  int p = nusers + pos[b];
  float val = x[u * 64 + lane] * x[p * 64 + lane];
#pragma unroll
  for (int m = 1; m < 64; m <<= 1) val += __shfl_xor(val, m, 64);
  if (lane == 0) out[b] = accumulate ? (out[b] + val) : val;
}

// fused layer: edge-parallel float4 gather-sum S (CSR buckets), matvec with
// W columns register-resident, leaky-relu, row L2 normalize.
// wave per node; lane = (edge-slot es = lane>>4, dim-group ds = lane&15).
__global__ __launch_bounds__(256) void layer_kernel(
    const float* __restrict__ xc, float* __restrict__ xn,
    const float* __restrict__ W1, const float* __restrict__ b1,
    const float* __restrict__ W2, const float* __restrict__ b2,
    const int* __restrict__ starts, const int* __restrict__ degs,
    const int2* __restrict__ ebuf, int nnodes) {
  const int lane = threadIdx.x & 63;
  const int wid = threadIdx.x >> 6;
  const int es = lane >> 4;   // edge slot 0..3
  const int ds = lane & 15;   // dim group: dims [4*ds, 4*ds+3]
  __shared__ float ash[4][64];
  __shared__ float gsh[4][64];

  // lane k holds column k of W1 and W2 (register-resident weights)
  float w1c[64], w2c[64];
#pragma unroll
  for (int j = 0; j < 64; ++j) {
    w1c[j] = W1[j * 64 + lane];
    w2c[j] = W2[j * 64 + lane];
  }
  const float b1k = b1[lane];
  const float b2k = b2[lane];

  const int wstride = gridDim.x * 4;
  for (int v = blockIdx.x * 4 + wid; v < nnodes; v += wstride) {
    const int e0 = __builtin_amdgcn_readfirstlane(starts[v]);
    const int dg = __builtin_amdgcn_readfirstlane(degs[v]);

    float4 S4 = make_float4(0.f, 0.f, 0.f, 0.f);
    float wacc = 0.f;
    // 16 edges per super-round: 4 indep meta loads -> 4 indep b128 gathers.
    for (int base = 0; base < dg; base += 16) {
      int idx[4];
      float wv[4];
#pragma unroll
      for (int r = 0; r < 4; ++r) {
        int e = base + r * 4 + es;
        int2 m = (e < dg) ? ebuf[e0 + e] : make_int2(0, 0);
        idx[r] = m.x << 6;  // row offset (src * 64)
        wv[r] = __int_as_float(m.y);
      }
      float4 g[4];
#pragma unroll
      for (int r = 0; r < 4; ++r)
        g[r] = *(const float4*)(xc + idx[r] + ds * 4);
#pragma unroll
      for (int r = 0; r < 4; ++r) {
        S4.x = fmaf(wv[r], g[r].x, S4.x);
        S4.y = fmaf(wv[r], g[r].y, S4.y);
        S4.z = fmaf(wv[r], g[r].z, S4.z);
        S4.w = fmaf(wv[r], g[r].w, S4.w);
        wacc += wv[r];
      }
    }
    // combine the 4 edge slots: stride-16 butterfly; afterwards EVERY lane
    // holds the full S for its dim-group and the full weight sum.
#pragma unroll
    for (int m = 16; m < 64; m <<= 1) {
      S4.x += __shfl_xor(S4.x, m, 64);
      S4.y += __shfl_xor(S4.y, m, 64);
      S4.z += __shfl_xor(S4.z, m, 64);
      S4.w += __shfl_xor(S4.w, m, 64);
      wacc += __shfl_xor(wacc, m, 64);
    }

    const float4 xk4 = *(const float4*)(xc + v * 64 + ds * 4);
    if (lane < 16) {
      float4 av = make_float4(S4.x + xk4.x, S4.y + xk4.y, S4.z + xk4.z,
                              S4.w + xk4.w);
      float4 gv = make_float4(S4.x * xk4.x, S4.y * xk4.y, S4.z * xk4.z,
                              S4.w * xk4.w);
      *(float4*)&ash[wid][lane * 4] = av;
      *(float4*)&gsh[wid][lane * 4] = gv;
    }
    asm volatile("" ::: "memory");  // order LDS writes before b128 reads

    float acc1 = 0.f, acc2 = 0.f;
#pragma unroll
    for (int q = 0; q < 16; ++q) {
      float4 av, gv;
      __builtin_memcpy(&av, &ash[wid][4 * q], 16);  // broadcast ds_read_b128
      __builtin_memcpy(&gv, &gsh[wid][4 * q], 16);
      acc1 = fmaf(av.x, w1c[4 * q + 0], acc1);
      acc1 = fmaf(av.y, w1c[4 * q + 1], acc1);
      acc1 = fmaf(av.z, w1c[4 * q + 2], acc1);
      acc1 = fmaf(av.w, w1c[4 * q + 3], acc1);
      acc2 = fmaf(gv.x, w2c[4 * q + 0], acc2);
      acc2 = fmaf(gv.y, w2c[4 * q + 1], acc2);
      acc2 = fmaf(gv.z, w2c[4 * q + 2], acc2);
      acc2 = fmaf(gv.w, w2c[4 * q + 3], acc2);
    }
    const float cv = wacc;
    float pre = acc1 + acc2 + (cv + 1.0f) * b1k + cv * b2k;
    float o = (pre > 0.0f) ? pre : 0.01f * pre;  // leaky relu, slope 0.01
    float ss = o * o;
#pragma unroll
    for (int m = 1; m < 64; m <<= 1) ss += __shfl_xor(ss, m, 64);
    float nrm = sqrtf(ss);
    xn[v * 64 + lane] = o / fmaxf(nrm, 1e-12f);
  }
}

extern "C" void kernel_launch(void* const* d_in, const int* in_sizes, int n_in,
                              void* d_out, int out_size, void* d_ws, size_t ws_size,
                              hipStream_t stream) {
  const float* Gu = (const float*)d_in[0];
  const float* Gi = (const float*)d_in[1];
  const float* W1 = (const float*)d_in[2];
  const float* b1 = (const float*)d_in[3];
  const float* W2 = (const float*)d_in[4];
  const float* b2 = (const float*)d_in[5];
  const float* ew = (const float*)d_in[6];
  const int* esrc = (const int*)d_in[7];
  const int* edst = (const int*)d_in[8];
  const int* user = (const int*)d_in[9];
  const int* pos = (const int*)d_in[10];
  float* out = (float*)d_out;

  const int NU = in_sizes[0] / 64;
  const int NI = in_sizes[1] / 64;
  const int N = NU + NI;
  const int E = in_sizes[6];
  const int B = in_sizes[9];

  char* ws = (char*)d_ws;
  size_t off = 0;
  auto carve = [&](size_t bytes) -> void* {
    void* p = ws + off;
    off = (off + bytes + 255) & ~(size_t)255;
    return p;
  };
  float* x0 = (float*)carve((size_t)N * 64 * 4);
  float* x1 = (float*)carve((size_t)N * 64 * 4);
  int2* ebuf = (int2*)carve((size_t)E * 8);
  int* startsA = (int*)carve((size_t)N * 4);
  int* cursor = (int*)carve((size_t)N * 4);
  int* counts = (int*)carve((size_t)N * 4);
  const int ntiles = (N + SCAN_TILE - 1) / SCAN_TILE;
  int* tsum = (int*)carve((size_t)ntiles * 4);

  hipMemsetAsync(counts, 0, (size_t)N * 4, stream);

  hist_kernel<<<(E + 255) / 256, 256, 0, stream>>>(edst, counts, E);
  tile_sum_kernel<<<ntiles, 256, 0, stream>>>(counts, tsum, N);
  tile_scan_kernel<<<1, 64, 0, stream>>>(tsum, ntiles);
  tile_write_kernel<<<ntiles, 256, 0, stream>>>(counts, tsum, startsA, cursor, N);
  place_kernel<<<(E + 255) / 256, 256, 0, stream>>>(esrc, edst, ew, cursor, ebuf, E);

  int nt4 = N * 64 / 4;
  int nu4 = NU * 64 / 4;
  init_x_kernel<<<(nt4 + 255) / 256, 256, 0, stream>>>(Gu, Gi, x0, nu4, nt4);
  dot_kernel<<<(B + 3) / 4, 256, 0, stream>>>(x0, user, pos, out, B, NU, 0);

  float* xc = x0;
  float* xn = x1;
  for (int l = 0; l < 3; ++l) {
    layer_kernel<<<768, 256, 0, stream>>>(xc, xn, W1 + l * 4096, b1 + l * 64,
                                          W2 + l * 4096, b2 + l * 64, startsA,
                                          counts, ebuf, N);
    dot_kernel<<<(B + 3) / 4, 256, 0, stream>>>(xn, user, pos, out, B, NU, 1);
    float* t = xc;
    xc = xn;
    xn = t;
  }
}

// Round 10
// 931.570 us; speedup vs baseline: 1.3591x; 1.3591x over previous
//
#include <hip/hip_runtime.h>

// ---------------------------------------------------------------------------
// NGCF forward, algebraically refactored:
//   per layer: S[v] = sum_{e: dst=v} w_e * x[src_e],  c[v] = sum w_e
//   out[v] = leakyrelu( (S+x)@W1 + (x*S)@W2 + (c+1)*b1 + c*b2 ), row-L2-norm
//   xui[b] = sum_l dot(x_l[user_b], x_l[NUM_USERS+pos_b])
// Edge buckets (CSR by dst, packed int2{src, w-bits}) built once per call.
// Layer: round-6 readlane-gather structure (empirically best: lane=dim,
// per-bucket metadata loaded cooperatively once, scalar addrs via readlane,
// 8 independent b32 gathers in flight). Grid raised 768->1536 blocks: round-7
// profile showed occupancy was grid-capped at 31% (3 blocks/CU) while
// VGPR=84 allows 6 blocks/CU -- latency-bound gather wants the waves.
// ---------------------------------------------------------------------------

#define SCAN_TILE 4096  // 256 threads x 16 elems
#define LAYER_GRID 1536 // 6 blocks/CU on 256 CUs (VGPR-capped occupancy)

__global__ __launch_bounds__(256) void init_x_kernel(
    const float* __restrict__ Gu, const float* __restrict__ Gi,
    float* __restrict__ x, int nu4, int nt4) {
  int i = blockIdx.x * 256 + threadIdx.x;
  if (i >= nt4) return;
  float4 v = (i < nu4) ? ((const float4*)Gu)[i] : ((const float4*)Gi)[i - nu4];
  ((float4*)x)[i] = v;
}

__global__ __launch_bounds__(256) void hist_kernel(
    const int* __restrict__ dst, int* __restrict__ counts, int E) {
  int e = blockIdx.x * 256 + threadIdx.x;
  if (e >= E) return;
  atomicAdd(&counts[dst[e]], 1);
}

// phase 1: per-tile sums
__global__ __launch_bounds__(256) void tile_sum_kernel(
    const int* __restrict__ counts, int* __restrict__ tsum, int n) {
  int tid = threadIdx.x;
  int lo = blockIdx.x * SCAN_TILE + tid * 16;
  int s = 0;
  if (lo + 16 <= n) {
    const int4* p = (const int4*)(counts + lo);
#pragma unroll
    for (int q = 0; q < 4; ++q) {
      int4 v = p[q];
      s += v.x + v.y + v.z + v.w;
    }
  } else {
    for (int i = lo; i < n && i < lo + 16; ++i) s += counts[i];
  }
#pragma unroll
  for (int m = 1; m < 64; m <<= 1) s += __shfl_xor(s, m, 64);
  __shared__ int red[4];
  if ((tid & 63) == 0) red[tid >> 6] = s;
  __syncthreads();
  if (tid == 0) tsum[blockIdx.x] = red[0] + red[1] + red[2] + red[3];
}

// phase 2: exclusive scan of tile sums (ntiles <= 64 -> one wave)
__global__ __launch_bounds__(64) void tile_scan_kernel(int* __restrict__ tsum,
                                                       int ntiles) {
  int lane = threadIdx.x;
  if (ntiles <= 64) {
    int v = (lane < ntiles) ? tsum[lane] : 0;
    int incl = v;
#pragma unroll
    for (int m = 1; m < 64; m <<= 1) {
      int t = __shfl_up(incl, m, 64);
      if (lane >= m) incl += t;
    }
    if (lane < ntiles) tsum[lane] = incl - v;
  } else if (lane == 0) {  // fallback, not expected at these sizes
    int run = 0;
    for (int i = 0; i < ntiles; ++i) {
      int t = tsum[i];
      tsum[i] = run;
      run += t;
    }
  }
}

// phase 3: per-tile exclusive scan + global offset -> starts, cursor
__global__ __launch_bounds__(256) void tile_write_kernel(
    const int* __restrict__ counts, const int* __restrict__ tsum,
    int* __restrict__ starts, int* __restrict__ cursor, int n) {
  int tid = threadIdx.x;
  int lo = blockIdx.x * SCAN_TILE + tid * 16;
  int c[16];
  int s = 0;
#pragma unroll
  for (int q = 0; q < 16; ++q) {
    int i = lo + q;
    int v = (i < n) ? counts[i] : 0;
    c[q] = v;
    s += v;
  }
  __shared__ int bs[256];
  bs[tid] = s;
  __syncthreads();
  int incl = s;
  for (int off = 1; off < 256; off <<= 1) {
    int t = (tid >= off) ? bs[tid - off] : 0;
    __syncthreads();
    incl += t;
    bs[tid] = incl;
    __syncthreads();
  }
  int run = tsum[blockIdx.x] + incl - s;
#pragma unroll
  for (int q = 0; q < 16; ++q) {
    int i = lo + q;
    if (i < n) {
      starts[i] = run;
      cursor[i] = run;
      run += c[q];
    }
  }
}

// pack {src, w-bits} into one 8B record -> single scattered store,
// single b64 metadata load per edge in the layer kernel.
__global__ __launch_bounds__(256) void place_kernel(
    const int* __restrict__ src, const int* __restrict__ dst,
    const float* __restrict__ w, int* __restrict__ cursor,
    int2* __restrict__ ebuf, int E) {
  int e = blockIdx.x * 256 + threadIdx.x;
  if (e >= E) return;
  int p = atomicAdd(&cursor[dst[e]], 1);
  ebuf[p] = make_int2(src[e], __float_as_int(w[e]));
}

// one wave per batch element; lane = dim; accumulate per-layer dot into out
__global__ __launch_bounds__(256) void dot_kernel(
    const float* __restrict__ x, const int* __restrict__ user,
    const int* __restrict__ pos, float* __restrict__ out,
    int batch, int nusers, int accumulate) {
  int b = blockIdx.x * 4 + (threadIdx.x >> 6);
  int lane = threadIdx.x & 63;
  if (b >= batch) return;
  int u = user[b];
  int p = nusers + pos[b];
  float val = x[u * 64 + lane] * x[p * 64 + lane];
#pragma unroll
  for (int m = 1; m < 64; m <<= 1) val += __shfl_xor(val, m, 64);
  if (lane == 0) out[b] = accumulate ? (out[b] + val) : val;
}

// fused: gather-sum S (CSR buckets, metadata broadcast via readlane),
// matvec with W cols, leaky-relu, row L2 normalize. wave per node, lane=dim.
__global__ __launch_bounds__(256) void layer_kernel(
    const float* __restrict__ xc, float* __restrict__ xn,
    const float* __restrict__ W1, const float* __restrict__ b1,
    const float* __restrict__ W2, const float* __restrict__ b2,
    const int* __restrict__ starts, const int* __restrict__ degs,
    const int2* __restrict__ ebuf, int nnodes) {
  const int lane = threadIdx.x & 63;
  const int wid = threadIdx.x >> 6;
  __shared__ float ash[4][64];
  __shared__ float gsh[4][64];

  // lane k holds column k of W1 and W2
  float w1c[64], w2c[64];
#pragma unroll
  for (int j = 0; j < 64; ++j) {
    w1c[j] = W1[j * 64 + lane];
    w2c[j] = W2[j * 64 + lane];
  }
  const float b1k = b1[lane];
  const float b2k = b2[lane];

  const int wstride = LAYER_GRID * 4;
  for (int v = blockIdx.x * 4 + wid; v < nnodes; v += wstride) {
    const float xk = xc[v * 64 + lane];
    int s0 = __builtin_amdgcn_readfirstlane(starts[v]);
    int dg = __builtin_amdgcn_readfirstlane(degs[v]);
    int nl = dg < 64 ? dg : 64;

    // one cooperative metadata load covers the whole bucket (deg<=64 path)
    int myidx = 0;
    float myw = 0.f;
    if (lane < nl) {
      int2 m = ebuf[s0 + lane];
      myidx = m.x << 6;
      myw = __int_as_float(m.y);
    }
    // c[v] = sum of edge weights: butterfly reduce (lanes >= nl hold 0)
    float wsum = myw;
#pragma unroll
    for (int m = 1; m < 64; m <<= 1) wsum += __shfl_xor(wsum, m, 64);

    float S = 0.f;
    int j = 0;
    for (; j + 8 <= nl; j += 8) {
      float vv[8], ww[8];
#pragma unroll
      for (int q = 0; q < 8; ++q) {
        int a = __builtin_amdgcn_readlane(myidx, j + q);  // scalar addr
        ww[q] = __uint_as_float(
            __builtin_amdgcn_readlane(__float_as_uint(myw), j + q));
        vv[q] = xc[a + lane];  // 8 independent gathers in flight
      }
#pragma unroll
      for (int q = 0; q < 8; ++q) S = fmaf(ww[q], vv[q], S);
    }
    for (; j < nl; ++j) {
      int a = __builtin_amdgcn_readlane(myidx, j);
      float w = __uint_as_float(
          __builtin_amdgcn_readlane(__float_as_uint(myw), j));
      S = fmaf(w, xc[a + lane], S);
    }
    // rare tail: degree > 64 (direct loads, also accumulate wsum)
    for (int e = s0 + 64; e < s0 + dg; ++e) {
      int2 m = ebuf[e];
      float w = __int_as_float(m.y);
      wsum += w;
      S = fmaf(w, xc[(m.x << 6) + lane], S);
    }

    ash[wid][lane] = S + xk;
    gsh[wid][lane] = S * xk;
    asm volatile("" ::: "memory");  // order LDS write before b128 reads

    float acc1 = 0.f, acc2 = 0.f;
#pragma unroll
    for (int q = 0; q < 16; ++q) {
      float4 av, gv;
      __builtin_memcpy(&av, &ash[wid][4 * q], 16);  // broadcast ds_read_b128
      __builtin_memcpy(&gv, &gsh[wid][4 * q], 16);
      acc1 = fmaf(av.x, w1c[4 * q + 0], acc1);
      acc1 = fmaf(av.y, w1c[4 * q + 1], acc1);
      acc1 = fmaf(av.z, w1c[4 * q + 2], acc1);
      acc1 = fmaf(av.w, w1c[4 * q + 3], acc1);
      acc2 = fmaf(gv.x, w2c[4 * q + 0], acc2);
      acc2 = fmaf(gv.y, w2c[4 * q + 1], acc2);
      acc2 = fmaf(gv.z, w2c[4 * q + 2], acc2);
      acc2 = fmaf(gv.w, w2c[4 * q + 3], acc2);
    }
    const float cv = wsum;
    float pre = acc1 + acc2 + (cv + 1.0f) * b1k + cv * b2k;
    float o = (pre > 0.0f) ? pre : 0.01f * pre;  // leaky relu, slope 0.01
    float ss = o * o;
#pragma unroll
    for (int m = 1; m < 64; m <<= 1) ss += __shfl_xor(ss, m, 64);
    float nrm = sqrtf(ss);
    xn[v * 64 + lane] = o / fmaxf(nrm, 1e-12f);
  }
}

extern "C" void kernel_launch(void* const* d_in, const int* in_sizes, int n_in,
                              void* d_out, int out_size, void* d_ws, size_t ws_size,
                              hipStream_t stream) {
  const float* Gu = (const float*)d_in[0];
  const float* Gi = (const float*)d_in[1];
  const float* W1 = (const float*)d_in[2];
  const float* b1 = (const float*)d_in[3];
  const float* W2 = (const float*)d_in[4];
  const float* b2 = (const float*)d_in[5];
  const float* ew = (const float*)d_in[6];
  const int* esrc = (const int*)d_in[7];
  const int* edst = (const int*)d_in[8];
  const int* user = (const int*)d_in[9];
  const int* pos = (const int*)d_in[10];
  float* out = (float*)d_out;

  const int NU = in_sizes[0] / 64;
  const int NI = in_sizes[1] / 64;
  const int N = NU + NI;
  const int E = in_sizes[6];
  const int B = in_sizes[9];

  char* ws = (char*)d_ws;
  size_t off = 0;
  auto carve = [&](size_t bytes) -> void* {
    void* p = ws + off;
    off = (off + bytes + 255) & ~(size_t)255;
    return p;
  };
  float* x0 = (float*)carve((size_t)N * 64 * 4);
  float* x1 = (float*)carve((size_t)N * 64 * 4);
  int2* ebuf = (int2*)carve((size_t)E * 8);
  int* startsA = (int*)carve((size_t)N * 4);
  int* cursor = (int*)carve((size_t)N * 4);
  int* counts = (int*)carve((size_t)N * 4);
  const int ntiles = (N + SCAN_TILE - 1) / SCAN_TILE;
  int* tsum = (int*)carve((size_t)ntiles * 4);

  hipMemsetAsync(counts, 0, (size_t)N * 4, stream);

  hist_kernel<<<(E + 255) / 256, 256, 0, stream>>>(edst, counts, E);
  tile_sum_kernel<<<ntiles, 256, 0, stream>>>(counts, tsum, N);
  tile_scan_kernel<<<1, 64, 0, stream>>>(tsum, ntiles);
  tile_write_kernel<<<ntiles, 256, 0, stream>>>(counts, tsum, startsA, cursor, N);
  place_kernel<<<(E + 255) / 256, 256, 0, stream>>>(esrc, edst, ew, cursor, ebuf, E);

  int nt4 = N * 64 / 4;
  int nu4 = NU * 64 / 4;
  init_x_kernel<<<(nt4 + 255) / 256, 256, 0, stream>>>(Gu, Gi, x0, nu4, nt4);
  dot_kernel<<<(B + 3) / 4, 256, 0, stream>>>(x0, user, pos, out, B, NU, 0);

  float* xc = x0;
  float* xn = x1;
  for (int l = 0; l < 3; ++l) {
    layer_kernel<<<LAYER_GRID, 256, 0, stream>>>(xc, xn, W1 + l * 4096,
                                                 b1 + l * 64, W2 + l * 4096,
                                                 b2 + l * 64, startsA, counts,
                                                 ebuf, N);
    dot_kernel<<<(B + 3) / 4, 256, 0, stream>>>(xn, user, pos, out, B, NU, 1);
    float* t = xc;
    xc = xn;
    xn = t;
  }
}